// Round 2
// baseline (36526.782 us; speedup 1.0000x reference)
//
#include <hip/hip_runtime.h>
#include <stdint.h>

// ComplexModel: 2-layer RNN(tanh) + 2-layer LSTM + FC on MI355X (gfx950)
// B=64 T=1024 D=256 H=256 HL=256 L=2 C=128
#define T_ 1024

typedef short bf16x8 __attribute__((ext_vector_type(8)));
typedef float f32x4  __attribute__((ext_vector_type(4)));
typedef unsigned short u16;

#define MFMA(a,b,c) __builtin_amdgcn_mfma_f32_16x16x32_bf16((a),(b),(c),0,0,0)

__device__ __forceinline__ u16 f2bf(float f){
  unsigned u = __float_as_uint(f);
  return (u16)((u + 0x7FFFu + ((u>>16)&1u)) >> 16);   // RNE
}
__device__ __forceinline__ float bf2f(u16 s){ return __uint_as_float(((unsigned)s)<<16); }
__device__ __forceinline__ float sigm(float x){ return 1.f/(1.f+__expf(-x)); }
__device__ __forceinline__ float tanhq(float x){ return 2.f/(1.f+__expf(-2.f*x)) - 1.f; }

__device__ __forceinline__ void gload16(const void* g, void* l){
  __builtin_amdgcn_global_load_lds(
      (const __attribute__((address_space(1))) unsigned int*)g,
      (__attribute__((address_space(3)))       unsigned int*)l, 16, 0, 0);
}
__device__ __forceinline__ void lgkm0_barrier(){
  asm volatile("s_waitcnt lgkmcnt(0)" ::: "memory");
  __builtin_amdgcn_s_barrier();
  asm volatile("" ::: "memory");
}

// ---- coherent (L1/L2-bypass, device-visible) memory ops via sc0 sc1 ----
__device__ __forceinline__ int coh_ld32(const int* p){
  int r;
  asm volatile("global_load_dword %0, %1, off sc0 sc1\n\ts_waitcnt vmcnt(0)"
               : "=v"(r) : "v"(p) : "memory");
  return r;
}
__device__ __forceinline__ void coh_st32(int* p, int v){
  asm volatile("global_store_dword %0, %1, off sc0 sc1" :: "v"(p), "v"(v) : "memory");
}
__device__ __forceinline__ void coh_st16(u16* p, u16 v){
  unsigned vv = v;
  asm volatile("global_store_short %0, %1, off sc0 sc1" :: "v"(p), "v"(vv) : "memory");
}
__device__ __forceinline__ void coh_ld_frags(const u16* base, bf16x8 a[8]){
  asm volatile("global_load_dwordx4 %0, %1, off sc0 sc1"            : "=v"(a[0]) : "v"(base) : "memory");
  asm volatile("global_load_dwordx4 %0, %1, off offset:64 sc0 sc1"  : "=v"(a[1]) : "v"(base) : "memory");
  asm volatile("global_load_dwordx4 %0, %1, off offset:128 sc0 sc1" : "=v"(a[2]) : "v"(base) : "memory");
  asm volatile("global_load_dwordx4 %0, %1, off offset:192 sc0 sc1" : "=v"(a[3]) : "v"(base) : "memory");
  asm volatile("global_load_dwordx4 %0, %1, off offset:256 sc0 sc1" : "=v"(a[4]) : "v"(base) : "memory");
  asm volatile("global_load_dwordx4 %0, %1, off offset:320 sc0 sc1" : "=v"(a[5]) : "v"(base) : "memory");
  asm volatile("global_load_dwordx4 %0, %1, off offset:384 sc0 sc1" : "=v"(a[6]) : "v"(base) : "memory");
  asm volatile("global_load_dwordx4 %0, %1, off offset:448 sc0 sc1" : "=v"(a[7]) : "v"(base) : "memory");
}
#define VMCNT(n) do{ asm volatile("s_waitcnt vmcnt(" #n ")" ::: "memory"); \
                     __builtin_amdgcn_sched_barrier(0); }while(0)

// ---------------- f32 -> bf16 conversion ----------------
__global__ void k_cvt(const float* __restrict__ s, u16* __restrict__ d, int n4){
  int i = blockIdx.x*blockDim.x + threadIdx.x;
  int stride = gridDim.x*blockDim.x;
  for (; i < n4; i += stride){
    float4 v = ((const float4*)s)[i];
    ushort4 o; o.x=f2bf(v.x); o.y=f2bf(v.y); o.z=f2bf(v.z); o.w=f2bf(v.w);
    ((ushort4*)d)[i] = o;
  }
}

// ---------------- bf16 GEMM: C[M,N] = A[M,256] @ B[N,256]^T ----------------
__global__ __launch_bounds__(256,2) void k_gemm(
    const u16* __restrict__ A, const u16* __restrict__ Bm,
    u16* __restrict__ C, int N)
{
  __shared__ u16 As[128*64];
  __shared__ u16 Bs[128*64];
  const int tid = threadIdx.x;
  const int lane = tid & 63, w = tid >> 6;
  const int l15 = lane & 15, l4 = lane >> 4;
  const long m0 = (long)blockIdx.x * 128;
  const int  n0 = blockIdx.y * 128;
  const int  mo = (w>>1)*64, no = (w&1)*64;

  f32x4 acc[4][4];
  #pragma unroll
  for (int i=0;i<4;++i)
    #pragma unroll
    for (int j=0;j<4;++j) acc[i][j] = (f32x4){0.f,0.f,0.f,0.f};

  for (int kt=0; kt<4; ++kt){
    const int k0 = kt*64;
    #pragma unroll
    for (int i=0;i<4;++i){
      int fb = (i*256+tid)*16;
      int r  = fb>>7, cbyte = fb&127;
      gload16(A + (m0 + r)*256 + k0 + (cbyte>>1), (char*)As + fb);
      gload16(Bm + (long)(n0 + r)*256 + k0 + (cbyte>>1), (char*)Bs + fb);
    }
    __syncthreads();
    #pragma unroll
    for (int kb=0;kb<2;++kb){
      bf16x8 a[4], b[4];
      #pragma unroll
      for (int mb=0;mb<4;++mb)
        a[mb] = *(const bf16x8*)(As + (mo+mb*16+l15)*64 + kb*32 + l4*8);
      #pragma unroll
      for (int nb=0;nb<4;++nb)
        b[nb] = *(const bf16x8*)(Bs + (no+nb*16+l15)*64 + kb*32 + l4*8);
      #pragma unroll
      for (int mb=0;mb<4;++mb)
        #pragma unroll
        for (int nb=0;nb<4;++nb)
          acc[mb][nb] = MFMA(a[mb], b[nb], acc[mb][nb]);
    }
    __syncthreads();
  }
  #pragma unroll
  for (int mb=0;mb<4;++mb)
    #pragma unroll
    for (int nb=0;nb<4;++nb)
      #pragma unroll
      for (int j=0;j<4;++j){
        long row = m0 + mo + mb*16 + l4*4 + j;
        int  col = n0 + no + nb*16 + l15;
        C[row*N + col] = f2bf(acc[mb][nb][j]);
      }
}

// ---------------- fused recurrence kernel ----------------
// blocks 0..3 : RNN, batch-split (16 rows each), Whh(hi/lo) in regs, h in LDS.
// blocks 4..7 : LSTM, one 64-unit hidden slice each; all 4 batch-chains
//               pipelined per super-step; h/flags via coherent (sc0 sc1) ops.
__global__ __launch_bounds__(512,2) void k_rec(
    const u16*  __restrict__ projR,  // [B*T][256] bf16
    const float* __restrict__ WhhR,  // [256][256]
    const float* __restrict__ bihR, const float* __restrict__ bhhR,
    u16* __restrict__ yR,            // [B*T][256] bf16 or null
    const u16*  __restrict__ projL,  // [B*T][1024] bf16
    const float* __restrict__ WhhL,  // [1024][256]
    const float* __restrict__ bihL, const float* __restrict__ bhhL,
    u16* __restrict__ yL,
    u16* __restrict__ hbuf,          // [2][64][256] bf16 LSTM h exchange
    int* __restrict__ flags,         // [4 bg][32 producer-wave] step counters
    float* __restrict__ feat,        // [64][512] f32 or null
    int lastMode)
{
  __shared__ u16 hlds[16*256];
  const int tid = threadIdx.x;
  const int lane = tid & 63, w = tid >> 6;
  const int l15 = lane & 15, l4 = lane >> 4, l7 = lane & 7;
  const int bid = blockIdx.x;
  (void)lastMode;

  if (bid < 4){
    // =============== RNN ===============
    const int g = bid;
    const int cb = 32*w;
    bf16x8 bhi[2][8], blo[2][8];
    #pragma unroll
    for (int nb=0;nb<2;++nb){
      const int col = cb + nb*16 + l15;
      #pragma unroll
      for (int kb=0;kb<8;++kb){
        const float* wp = WhhR + (long)col*256 + kb*32 + l4*8;
        #pragma unroll
        for (int j=0;j<8;++j){
          float wv = wp[j];
          u16 hi = f2bf(wv);
          bhi[nb][kb][j] = (short)hi;
          blo[nb][kb][j] = (short)f2bf(wv - bf2f(hi));
        }
      }
    }
    float bias[2];
    #pragma unroll
    for (int nb=0;nb<2;++nb){ int col = cb+nb*16+l15; bias[nb]=bihR[col]+bhhR[col]; }

    u16 pfr[8];
    #pragma unroll
    for (int nb=0;nb<2;++nb)
      #pragma unroll
      for (int j=0;j<4;++j)
        pfr[nb*4+j] = projR[((long)(16*g + l4*4 + j)*T_ + 0)*256 + cb + nb*16 + l15];

    for (int t=0; t<T_; ++t){
      lgkm0_barrier();
      f32x4 acc0 = {0.f,0.f,0.f,0.f}, acc1 = acc0;
      if (t > 0){
        bf16x8 a[8];
        #pragma unroll
        for (int kb=0;kb<8;++kb){
          int bo = (l15*512 + kb*64 + l4*16) ^ ((l15&7)<<4);
          a[kb] = *(const bf16x8*)((const char*)hlds + bo);
        }
        #pragma unroll
        for (int kb=0;kb<8;++kb){
          acc0 = MFMA(a[kb], bhi[0][kb], acc0);
          acc0 = MFMA(a[kb], blo[0][kb], acc0);
          acc1 = MFMA(a[kb], bhi[1][kb], acc1);
          acc1 = MFMA(a[kb], blo[1][kb], acc1);
        }
      }
      float hv[2][4];
      #pragma unroll
      for (int nb=0;nb<2;++nb)
        #pragma unroll
        for (int j=0;j<4;++j){
          float pre = (nb ? acc1[j] : acc0[j]) + bf2f(pfr[nb*4+j]) + bias[nb];
          hv[nb][j] = tanhq(pre);
        }
      int tn = (t+1 < T_) ? t+1 : t;
      #pragma unroll
      for (int nb=0;nb<2;++nb)
        #pragma unroll
        for (int j=0;j<4;++j)
          pfr[nb*4+j] = projR[((long)(16*g + l4*4 + j)*T_ + tn)*256 + cb + nb*16 + l15];
      lgkm0_barrier();
      #pragma unroll
      for (int nb=0;nb<2;++nb)
        #pragma unroll
        for (int j=0;j<4;++j){
          int m = l4*4 + j, u = cb + nb*16 + l15;
          u16 hb = f2bf(hv[nb][j]);
          int bo = (m*512 + u*2) ^ ((m&7)<<4);
          *(u16*)((char*)hlds + bo) = hb;
          if (yR) yR[((long)(16*g+m)*T_ + t)*256 + u] = hb;
          if (feat && t == T_-1) feat[(16*g+m)*512 + u] = hv[nb][j];
        }
    }
  } else {
    // =============== LSTM: 4 chains pipelined per super-step ===============
    const int hg = bid - 4;          // hidden slice 0..3
    const int ub = 64*hg + 8*w;      // wave's 8 hidden units
    const int ugl = ub + l7;
    bf16x8 bhi[2][8], blo[2][8];
    float bias[2];
    #pragma unroll
    for (int nb=0;nb<2;++nb){
      const int gate = nb*2 + (l15>>3);
      const long wr = (long)(gate*256 + ugl);
      bias[nb] = bihL[wr] + bhhL[wr];
      #pragma unroll
      for (int kb=0;kb<8;++kb){
        const float* wp = WhhL + wr*256 + kb*32 + l4*8;
        #pragma unroll
        for (int j=0;j<8;++j){
          float wv = wp[j];
          u16 hi = f2bf(wv);
          bhi[nb][kb][j] = (short)hi;
          blo[nb][kb][j] = (short)f2bf(wv - bf2f(hi));
        }
      }
    }
    u16 pfr[4][8];
    #pragma unroll
    for (int bg=0;bg<4;++bg)
      #pragma unroll
      for (int nb=0;nb<2;++nb){
        const int gate = nb*2 + (l15>>3);
        #pragma unroll
        for (int j=0;j<4;++j)
          pfr[bg][nb*4+j] = projL[((long)(16*bg + l4*4 + j)*T_ + 0)*1024 + gate*256 + ugl];
      }
    float cst[4][4];
    #pragma unroll
    for (int bg=0;bg<4;++bg){ cst[bg][0]=0.f;cst[bg][1]=0.f;cst[bg][2]=0.f;cst[bg][3]=0.f; }
    const bool lowHalf = ((lane & 8) == 0);
    int* flg = flags;                // [bg][32]

    for (int t=0; t<T_; ++t){
      const int par = t & 1, pn = par ^ 1;
      bf16x8 afr[8];
      if (t > 0){
        // single poll for all 4 chains (128 flag words, 2 loads/lane)
        while (true){
          int a0 = coh_ld32(flg + lane);
          int a1 = coh_ld32(flg + 64 + lane);
          if (__all((a0 >= t) & (a1 >= t))) break;
          __builtin_amdgcn_s_sleep(2);
        }
        coh_ld_frags(hbuf + par*16384 + l15*256 + l4*8, afr);   // chain 0
      }
      #pragma unroll
      for (int bg=0;bg<4;++bg){
        f32x4 acc0={0.f,0.f,0.f,0.f}, acc1={0.f,0.f,0.f,0.f};
        if (t > 0){
          if (bg == 0){ VMCNT(0); } else { VMCNT(12); }   // frags ready; stores/pfr stay in flight
          #pragma unroll
          for (int kb=0;kb<8;++kb){
            acc0 = MFMA(afr[kb], bhi[0][kb], acc0);
            acc0 = MFMA(afr[kb], blo[0][kb], acc0);
            acc1 = MFMA(afr[kb], bhi[1][kb], acc1);
            acc1 = MFMA(afr[kb], blo[1][kb], acc1);
          }
          if (bg < 3)   // next chain's frags issue under this chain's act/store
            coh_ld_frags(hbuf + par*16384 + (16*(bg+1)+l15)*256 + l4*8, afr);
        }
        #pragma unroll
        for (int j=0;j<4;++j){
          float s0 = acc0[j] + bf2f(pfr[bg][j])   + bias[0];
          float s1 = acc1[j] + bf2f(pfr[bg][4+j]) + bias[1];
          float g0 = sigm(s0);
          float g1 = lowHalf ? tanhq(s1) : sigm(s1);
          float p0 = __shfl_xor(g0, 8);
          float p1 = __shfl_xor(g1, 8);
          float iv = lowHalf ? g0 : p0;
          float fv = lowHalf ? p0 : g0;
          float gv = lowHalf ? g1 : p1;
          float ov = lowHalf ? p1 : g1;
          float cv = fv * cst[bg][j] + iv * gv;
          cst[bg][j] = cv;
          float hval = ov * tanhq(cv);
          const int m = 16*bg + l4*4 + j;
          if (lowHalf){
            u16 hb2 = f2bf(hval);
            coh_st16(hbuf + pn*16384 + m*256 + ugl, hb2);
            if (yL) yL[((long)m*T_ + t)*256 + ugl] = hb2;
            if (feat && t == T_-1) feat[m*512 + 256 + ugl] = hval;
          }
        }
        const int tn = (t+1 < T_) ? t+1 : t;
        #pragma unroll
        for (int nb=0;nb<2;++nb){
          const int gate = nb*2 + (l15>>3);
          #pragma unroll
          for (int j=0;j<4;++j)
            pfr[bg][nb*4+j] = projL[((long)(16*bg + l4*4 + j)*T_ + tn)*1024 + gate*256 + ugl];
        }
      }
      // drain all h-stores (pfr prefetch of chain 3 may stay in flight), publish
      asm volatile("s_waitcnt vmcnt(8)" ::: "memory");
      if (lane < 4) coh_st32(flg + lane*32 + hg*8 + w, t+1);
    }
  }
}

// ---------------- FC ----------------
__global__ void k_fc(const float* __restrict__ feat, const float* __restrict__ W,
                     const float* __restrict__ bias, float* __restrict__ out){
  int o = blockIdx.x*blockDim.x + threadIdx.x;
  if (o >= 64*128) return;
  int b = o >> 7, c = o & 127;
  float s = bias[c];
  const float* f  = feat + b*512;
  const float* wr = W + c*512;
  #pragma unroll 8
  for (int k=0;k<512;++k) s += f[k]*wr[k];
  out[o] = s;
}

extern "C" void kernel_launch(void* const* d_in, const int* in_sizes, int n_in,
                              void* d_out, int out_size, void* d_ws, size_t ws_size,
                              hipStream_t stream)
{
  (void)in_sizes; (void)n_in; (void)out_size; (void)ws_size;
  const float* rnn_x    = (const float*)d_in[0];
  const float* lstm_x   = (const float*)d_in[1];
  const float* rnn_Wih  = (const float*)d_in[2];
  const float* rnn_Whh  = (const float*)d_in[3];
  const float* rnn_bih  = (const float*)d_in[4];
  const float* rnn_bhh  = (const float*)d_in[5];
  const float* lstm_Wih = (const float*)d_in[6];
  const float* lstm_Whh = (const float*)d_in[7];
  const float* lstm_bih = (const float*)d_in[8];
  const float* lstm_bhh = (const float*)d_in[9];
  const float* fc_W     = (const float*)d_in[10];
  const float* fc_b     = (const float*)d_in[11];
  float* out = (float*)d_out;

  char* ws = (char*)d_ws; size_t off = 0;
  auto alloc = [&](size_t b)->char*{ char* p = ws + off; off += (b + 255) & ~(size_t)255; return p; };
  const size_t NE = (size_t)64*1024*256;
  u16*  wih_r = (u16*)alloc(2*256*256*2);
  u16*  wih_l = (u16*)alloc(2*1024*256*2);
  u16*  xr    = (u16*)alloc(NE*2);
  u16*  xl    = (u16*)alloc(NE*2);
  u16*  projR = (u16*)alloc(NE*2);
  u16*  projL = (u16*)alloc(NE*4*2);
  u16*  hbuf  = (u16*)alloc(2*64*256*2);
  int*  flags = (int*)alloc(1024);                // 2 layers x 128 words
  float* feat = (float*)alloc(64*512*4);

  hipMemsetAsync(flags, 0, 1024, stream);
  k_cvt<<<2048,256,0,stream>>>(rnn_x,  xr, (int)(NE/4));
  k_cvt<<<2048,256,0,stream>>>(lstm_x, xl, (int)(NE/4));
  k_cvt<<<64, 256,0,stream>>>(rnn_Wih,  wih_r, 2*256*256/4);
  k_cvt<<<256,256,0,stream>>>(lstm_Wih, wih_l, 2*1024*256/4);
  k_gemm<<<dim3(512,2),256,0,stream>>>(xr, wih_r, projR, 256);
  k_gemm<<<dim3(512,8),256,0,stream>>>(xl, wih_l, projL, 1024);
  k_rec<<<8,512,0,stream>>>(projR, rnn_Whh, rnn_bih, rnn_bhh, xr,
                            projL, lstm_Whh, lstm_bih, lstm_bhh, xl,
                            hbuf, flags, nullptr, 0);
  k_gemm<<<dim3(512,2),256,0,stream>>>(xr, wih_r + 256*256,  projR, 256);
  k_gemm<<<dim3(512,8),256,0,stream>>>(xl, wih_l + 1024*256, projL, 1024);
  k_rec<<<8,512,0,stream>>>(projR, rnn_Whh + 256*256, rnn_bih + 256, rnn_bhh + 256, nullptr,
                            projL, lstm_Whh + 1024*256, lstm_bih + 1024, lstm_bhh + 1024, nullptr,
                            hbuf, flags + 128, feat, 1);
  k_fc<<<32,256,0,stream>>>(feat, fc_W, fc_b, out);
}

// Round 3
// 21601.892 us; speedup vs baseline: 1.6909x; 1.6909x over previous
//
#include <hip/hip_runtime.h>
#include <stdint.h>

// ComplexModel: 2-layer RNN(tanh) + 2-layer LSTM + FC on MI355X (gfx950)
// B=64 T=1024 D=256 H=256 HL=256 L=2 C=128
#define T_ 1024

typedef short bf16x8 __attribute__((ext_vector_type(8)));
typedef float f32x4  __attribute__((ext_vector_type(4)));
typedef int   i32x4  __attribute__((ext_vector_type(4)));
typedef unsigned short u16;

#define MFMA(a,b,c) __builtin_amdgcn_mfma_f32_16x16x32_bf16((a),(b),(c),0,0,0)

__device__ __forceinline__ u16 f2bf(float f){
  unsigned u = __float_as_uint(f);
  return (u16)((u + 0x7FFFu + ((u>>16)&1u)) >> 16);   // RNE
}
__device__ __forceinline__ float bf2f(u16 s){ return __uint_as_float(((unsigned)s)<<16); }
__device__ __forceinline__ float sigm(float x){ return 1.f/(1.f+__expf(-x)); }
__device__ __forceinline__ float tanhq(float x){ return 2.f/(1.f+__expf(-2.f*x)) - 1.f; }

__device__ __forceinline__ void gload16(const void* g, void* l){
  __builtin_amdgcn_global_load_lds(
      (const __attribute__((address_space(1))) unsigned int*)g,
      (__attribute__((address_space(3)))       unsigned int*)l, 16, 0, 0);
}
// barrier draining LDS only (global prefetches stay in flight)
__device__ __forceinline__ void lgkm0_barrier(){
  asm volatile("s_waitcnt lgkmcnt(0)" ::: "memory");
  __builtin_amdgcn_s_barrier();
  asm volatile("" ::: "memory");
}

#define VMCNT(n) do{ asm volatile("s_waitcnt vmcnt(" #n ")" ::: "memory"); \
                     __builtin_amdgcn_sched_barrier(0); }while(0)
// coherent (device-visible) 16B load / dword store
#define LD_X4(dst, p, OFF) asm volatile("global_load_dwordx4 %0, %1, off offset:" #OFF " sc0 sc1" : "=v"(dst) : "v"(p) : "memory")
#define ST_TAG(p, v)       asm volatile("global_store_dword %0, %1, off sc0 sc1" :: "v"(p), "v"(v) : "memory")
// normal cached u16 load
#define LD_U16(dst, p, OFF) asm volatile("global_load_ushort %0, %1, off offset:" #OFF : "=v"(dst) : "v"(p) : "memory")

// ---------------- f32 -> bf16 conversion ----------------
__global__ void k_cvt(const float* __restrict__ s, u16* __restrict__ d, int n4){
  int i = blockIdx.x*blockDim.x + threadIdx.x;
  int stride = gridDim.x*blockDim.x;
  for (; i < n4; i += stride){
    float4 v = ((const float4*)s)[i];
    ushort4 o; o.x=f2bf(v.x); o.y=f2bf(v.y); o.z=f2bf(v.z); o.w=f2bf(v.w);
    ((ushort4*)d)[i] = o;
  }
}

// ---------------- bf16 GEMM: C[(t*64+b), N] = A[b*T+t][256] @ B[N,256]^T ----
// output written TRANSPOSED to [t][b] blocks so k_rec reads are step-local.
__global__ __launch_bounds__(256,2) void k_gemm(
    const u16* __restrict__ A, const u16* __restrict__ Bm,
    u16* __restrict__ C, int N)
{
  __shared__ u16 As[128*64];
  __shared__ u16 Bs[128*64];
  const int tid = threadIdx.x;
  const int lane = tid & 63, w = tid >> 6;
  const int l15 = lane & 15, l4 = lane >> 4;
  const long m0 = (long)blockIdx.x * 128;
  const int  n0 = blockIdx.y * 128;
  const int  mo = (w>>1)*64, no = (w&1)*64;

  f32x4 acc[4][4];
  #pragma unroll
  for (int i=0;i<4;++i)
    #pragma unroll
    for (int j=0;j<4;++j) acc[i][j] = (f32x4){0.f,0.f,0.f,0.f};

  for (int kt=0; kt<4; ++kt){
    const int k0 = kt*64;
    #pragma unroll
    for (int i=0;i<4;++i){
      int fb = (i*256+tid)*16;
      int r  = fb>>7, cbyte = fb&127;
      gload16(A + (m0 + r)*256 + k0 + (cbyte>>1), (char*)As + fb);
      gload16(Bm + (long)(n0 + r)*256 + k0 + (cbyte>>1), (char*)Bs + fb);
    }
    __syncthreads();
    #pragma unroll
    for (int kb=0;kb<2;++kb){
      bf16x8 a[4], b[4];
      #pragma unroll
      for (int mb=0;mb<4;++mb)
        a[mb] = *(const bf16x8*)(As + (mo+mb*16+l15)*64 + kb*32 + l4*8);
      #pragma unroll
      for (int nb=0;nb<4;++nb)
        b[nb] = *(const bf16x8*)(Bs + (no+nb*16+l15)*64 + kb*32 + l4*8);
      #pragma unroll
      for (int mb=0;mb<4;++mb)
        #pragma unroll
        for (int nb=0;nb<4;++nb)
          acc[mb][nb] = MFMA(a[mb], b[nb], acc[mb][nb]);
    }
    __syncthreads();
  }
  #pragma unroll
  for (int mb=0;mb<4;++mb)
    #pragma unroll
    for (int nb=0;nb<4;++nb)
      #pragma unroll
      for (int j=0;j<4;++j){
        long m   = m0 + mo + mb*16 + l4*4 + j;       // m = b*1024 + t
        long crow= (long)(m & 1023)*64 + (m >> 10);  // -> t*64 + b
        int  col = n0 + no + nb*16 + l15;
        C[crow*N + col] = f2bf(acc[mb][nb][j]);
      }
}

// ---------------- fused recurrence kernel ----------------
// blocks 0..3 : RNN, batch-split (16 rows), Whh(hi/lo) in regs, h in LDS.
// blocks 4..7 : LSTM, one 64-unit slice each; 4 batch-chains per step,
//               h exchanged via self-TAGGED dwords in hbuf (no flags/fences).
__global__ __launch_bounds__(512,2) void k_rec(
    const u16*  __restrict__ projR,  // [t*64+b][256] bf16
    const float* __restrict__ WhhR,
    const float* __restrict__ bihR, const float* __restrict__ bhhR,
    u16* __restrict__ yR,            // [b*T+t][256] bf16 or null
    const u16*  __restrict__ projL,  // [t*64+b][1024] bf16
    const float* __restrict__ WhhL,
    const float* __restrict__ bihL, const float* __restrict__ bhhL,
    u16* __restrict__ yL,            // [b*T+t][256] bf16 (never null; dummy for L2)
    unsigned* __restrict__ hbuf,     // u32 [2][64][256]: (tag16<<16)|h_bf16
    float* __restrict__ feat,        // [64][512] f32 or null
    int lay)
{
  __shared__ u16 hlds[16*256];       // RNN h
  __shared__ u16 lsm[2*16*256];      // LSTM staged h (2 bufs x 8KB)
  const int tid = threadIdx.x;
  const int lane = tid & 63, w = tid >> 6;
  const int l15 = lane & 15, l4 = lane >> 4, l7 = lane & 7;
  const int bid = blockIdx.x;

  if (bid < 4){
    // =============== RNN ===============
    const int g = bid;
    const int cb = 32*w;
    bf16x8 bhi[2][8], blo[2][8];
    #pragma unroll
    for (int nb=0;nb<2;++nb){
      const int col = cb + nb*16 + l15;
      #pragma unroll
      for (int kb=0;kb<8;++kb){
        const float* wp = WhhR + (long)col*256 + kb*32 + l4*8;
        #pragma unroll
        for (int j=0;j<8;++j){
          float wv = wp[j];
          u16 hi = f2bf(wv);
          bhi[nb][kb][j] = (short)hi;
          blo[nb][kb][j] = (short)f2bf(wv - bf2f(hi));
        }
      }
    }
    float bias[2];
    #pragma unroll
    for (int nb=0;nb<2;++nb){ int col = cb+nb*16+l15; bias[nb]=bihR[col]+bhhR[col]; }

    u16 pfr[8];
    #pragma unroll
    for (int nb=0;nb<2;++nb)
      #pragma unroll
      for (int j=0;j<4;++j)
        pfr[nb*4+j] = projR[(long)(0*64 + 16*g + l4*4 + j)*256 + cb + nb*16 + l15];

    for (int t=0; t<T_; ++t){
      lgkm0_barrier();
      f32x4 acc0 = {0.f,0.f,0.f,0.f}, acc1 = acc0;
      if (t > 0){
        bf16x8 a[8];
        #pragma unroll
        for (int kb=0;kb<8;++kb){
          int bo = (l15*512 + kb*64 + l4*16) ^ ((l15&7)<<4);
          a[kb] = *(const bf16x8*)((const char*)hlds + bo);
        }
        #pragma unroll
        for (int kb=0;kb<8;++kb){
          acc0 = MFMA(a[kb], bhi[0][kb], acc0);
          acc0 = MFMA(a[kb], blo[0][kb], acc0);
          acc1 = MFMA(a[kb], bhi[1][kb], acc1);
          acc1 = MFMA(a[kb], blo[1][kb], acc1);
        }
      }
      float hv[2][4];
      #pragma unroll
      for (int nb=0;nb<2;++nb)
        #pragma unroll
        for (int j=0;j<4;++j){
          float pre = (nb ? acc1[j] : acc0[j]) + bf2f(pfr[nb*4+j]) + bias[nb];
          hv[nb][j] = tanhq(pre);
        }
      int tn = (t+1 < T_) ? t+1 : t;
      #pragma unroll
      for (int nb=0;nb<2;++nb)
        #pragma unroll
        for (int j=0;j<4;++j)
          pfr[nb*4+j] = projR[(long)(tn*64 + 16*g + l4*4 + j)*256 + cb + nb*16 + l15];
      lgkm0_barrier();
      #pragma unroll
      for (int nb=0;nb<2;++nb)
        #pragma unroll
        for (int j=0;j<4;++j){
          int m = l4*4 + j, u = cb + nb*16 + l15;
          u16 hb = f2bf(hv[nb][j]);
          int bo = (m*512 + u*2) ^ ((m&7)<<4);
          *(u16*)((char*)hlds + bo) = hb;
          if (yR) yR[((long)(16*g+m)*T_ + t)*256 + u] = hb;
          if (feat && t == T_-1) feat[(16*g+m)*512 + u] = hv[nb][j];
        }
    }
  } else {
    // =============== LSTM: tagged-transport, LDS-staged ===============
    const int hg = bid - 4;
    const int ub = 64*hg + 8*w;
    const int ugl = ub + l7;
    const int srow  = 2*w + (lane>>5);        // staged LDS row this lane fills
    const int scol8 = (lane&31)*8;            // dword col (8 units)
    const int swro  = ((srow*512 + (lane&31)*16) ^ ((srow&7)<<4));
    char* lsmBE = (char*)lsm;
    char* lsmBO = (char*)lsm + 8192;

    bf16x8 bhi[2][8], blo[2][8];
    float bias[2];
    #pragma unroll
    for (int nb=0;nb<2;++nb){
      const int gate = nb*2 + (l15>>3);
      const long wr = (long)(gate*256 + ugl);
      bias[nb] = bihL[wr] + bhhL[wr];
      #pragma unroll
      for (int kb=0;kb<8;++kb){
        const float* wp = WhhL + wr*256 + kb*32 + l4*8;
        #pragma unroll
        for (int j=0;j<8;++j){
          float wv = wp[j];
          u16 hi = f2bf(wv);
          bhi[nb][kb][j] = (short)hi;
          blo[nb][kb][j] = (short)f2bf(wv - bf2f(hi));
        }
      }
    }
    float cst[4][4];
    #pragma unroll
    for (int b_=0;b_<4;++b_){ cst[b_][0]=0.f;cst[b_][1]=0.f;cst[b_][2]=0.f;cst[b_][3]=0.f; }
    const bool lowHalf = ((lane & 8) == 0);
    i32x4 rE0, rE1, rO0, rO1;
    unsigned pfE[8], pfO[8];

    // pfr issue helper values
    #define PFR_ISSUE(PF, TP, BGP) do{                                             \
      const u16* pb  = projL + ((size_t)((TP)*64 + 16*(BGP) + l4*4)*1024 + (l15>>3)*256 + ugl); \
      const u16* pb2 = pb + 2048;                                                  \
      LD_U16(PF[0], pb, 0);    LD_U16(PF[4], pb, 1024);                            \
      LD_U16(PF[1], pb, 2048); LD_U16(PF[5], pb, 3072);                            \
      LD_U16(PF[2], pb2, 0);    LD_U16(PF[6], pb2, 1024);                          \
      LD_U16(PF[3], pb2, 2048); LD_U16(PF[7], pb2, 3072);                          \
    }while(0)

    #define STAGE_ISSUE(R0, R1, T2, BG2) do{                                       \
      const unsigned* sp = hbuf + ((T2)&1)*16384 + (16*(BG2) + srow)*256 + scol8;  \
      LD_X4(R0, sp, 0); LD_X4(R1, sp, 16);                                         \
    }while(0)

    #define LACT(BG, PF, TT) do{                                                   \
      const unsigned tws = (unsigned)(((lay<<13)|((BG)<<11)|((TT)+1))<<16);        \
      unsigned* hstb = hbuf + (((TT)&1)^1)*16384 + (16*(BG) + l4*4)*256 + ugl;     \
      _Pragma("unroll")                                                            \
      for (int j=0;j<4;++j){                                                       \
        float s0v = acc0[j] + bf2f((u16)PF[j])   + bias[0];                        \
        float s1v = acc1[j] + bf2f((u16)PF[4+j]) + bias[1];                        \
        float g0 = sigm(s0v);                                                      \
        float g1 = lowHalf ? tanhq(s1v) : sigm(s1v);                               \
        float p0 = __shfl_xor(g0, 8);                                              \
        float p1 = __shfl_xor(g1, 8);                                              \
        float iv = lowHalf ? g0 : p0;                                              \
        float fv = lowHalf ? p0 : g0;                                              \
        float gv = lowHalf ? g1 : p1;                                              \
        float ov = lowHalf ? p1 : g1;                                              \
        float cv = fv * cst[BG][j] + iv * gv;                                      \
        cst[BG][j] = cv;                                                           \
        float hval = ov * tanhq(cv);                                               \
        if (lowHalf){                                                              \
          u16 hb2 = f2bf(hval);                                                    \
          unsigned dw = tws | (unsigned)hb2;                                       \
          ST_TAG(hstb + j*256, dw);                                                \
          yL[((long)(16*(BG) + l4*4 + j)*T_ + (TT))*256 + ugl] = hb2;              \
          if (feat && (TT) == T_-1) feat[(16*(BG)+l4*4+j)*512 + 256 + ugl] = hval; \
        }                                                                          \
      }                                                                            \
    }while(0)

    // ---- prologue t=0 (no recurrent input) ----
    PFR_ISSUE(pfE, 0, 0);
    PFR_ISSUE(pfO, 0, 1);
    VMCNT(0);
    {
      f32x4 acc0 = {0.f,0.f,0.f,0.f}, acc1 = {0.f,0.f,0.f,0.f};
      LACT(0, pfE, 0); PFR_ISSUE(pfE, 0, 2);
      LACT(1, pfO, 0); PFR_ISSUE(pfO, 0, 3);
      STAGE_ISSUE(rE0, rE1, 1, 0); VMCNT(0);
      LACT(2, pfE, 0); PFR_ISSUE(pfE, 1, 0);
      STAGE_ISSUE(rO0, rO1, 1, 1); VMCNT(0);
      LACT(3, pfO, 0); PFR_ISSUE(pfO, 1, 1);
    }

    // ---- steady slots ----
    #define LSLOT(BG, R0, R1, PF, LSB) do{                                         \
      VMCNT(34);                                                                   \
      {                                                                            \
        const unsigned tw = (unsigned)(((lay<<13)|((BG)<<11)|t)<<16);              \
        for(;;){                                                                   \
          unsigned bad;                                                            \
          bad  = (unsigned)(R0[0]^(int)tw)&0xFFFF0000u;                            \
          bad |= (unsigned)(R0[1]^(int)tw)&0xFFFF0000u;                            \
          bad |= (unsigned)(R0[2]^(int)tw)&0xFFFF0000u;                            \
          bad |= (unsigned)(R0[3]^(int)tw)&0xFFFF0000u;                            \
          bad |= (unsigned)(R1[0]^(int)tw)&0xFFFF0000u;                            \
          bad |= (unsigned)(R1[1]^(int)tw)&0xFFFF0000u;                            \
          bad |= (unsigned)(R1[2]^(int)tw)&0xFFFF0000u;                            \
          bad |= (unsigned)(R1[3]^(int)tw)&0xFFFF0000u;                            \
          if (!__any(bad != 0u)) break;                                            \
          STAGE_ISSUE(R0, R1, t, BG); VMCNT(0);                                    \
        }                                                                          \
        i32x4 pk;                                                                  \
        pk[0]=(int)__builtin_amdgcn_perm((unsigned)R0[1],(unsigned)R0[0],0x05040100u); \
        pk[1]=(int)__builtin_amdgcn_perm((unsigned)R0[3],(unsigned)R0[2],0x05040100u); \
        pk[2]=(int)__builtin_amdgcn_perm((unsigned)R1[1],(unsigned)R1[0],0x05040100u); \
        pk[3]=(int)__builtin_amdgcn_perm((unsigned)R1[3],(unsigned)R1[2],0x05040100u); \
        *(i32x4*)(lsmB##LSB + swro) = pk;                                          \
      }                                                                            \
      { int t2 = t + ((BG)>=2 ? 1:0); if (t2 > T_-1) t2 = T_-1;                    \
        STAGE_ISSUE(R0, R1, t2, ((BG)+2)&3); }                                     \
      lgkm0_barrier();                                                             \
      f32x4 acc0 = {0.f,0.f,0.f,0.f}, acc1 = {0.f,0.f,0.f,0.f};                    \
      _Pragma("unroll")                                                            \
      for (int kb=0;kb<8;++kb){                                                    \
        bf16x8 a = *(const bf16x8*)(lsmB##LSB + ((l15*512 + kb*64 + l4*16) ^ ((l15&7)<<4))); \
        acc0 = MFMA(a, bhi[0][kb], acc0);  acc0 = MFMA(a, blo[0][kb], acc0);       \
        acc1 = MFMA(a, bhi[1][kb], acc1);  acc1 = MFMA(a, blo[1][kb], acc1);       \
      }                                                                            \
      VMCNT(20);                                                                   \
      LACT(BG, PF, t);                                                             \
      { int tp = t + ((BG)>=2 ? 1:0); if (tp > T_-1) tp = T_-1;                    \
        PFR_ISSUE(PF, tp, ((BG)+2)&3); }                                           \
    }while(0)

    for (int t=1; t<T_; ++t){
      LSLOT(0, rE0, rE1, pfE, E);
      LSLOT(1, rO0, rO1, pfO, O);
      LSLOT(2, rE0, rE1, pfE, E);
      LSLOT(3, rO0, rO1, pfO, O);
    }
    VMCNT(0);
  }
}

// ---------------- FC ----------------
__global__ void k_fc(const float* __restrict__ feat, const float* __restrict__ W,
                     const float* __restrict__ bias, float* __restrict__ out){
  int o = blockIdx.x*blockDim.x + threadIdx.x;
  if (o >= 64*128) return;
  int b = o >> 7, c = o & 127;
  float s = bias[c];
  const float* f  = feat + b*512;
  const float* wr = W + c*512;
  #pragma unroll 8
  for (int k=0;k<512;++k) s += f[k]*wr[k];
  out[o] = s;
}

extern "C" void kernel_launch(void* const* d_in, const int* in_sizes, int n_in,
                              void* d_out, int out_size, void* d_ws, size_t ws_size,
                              hipStream_t stream)
{
  (void)in_sizes; (void)n_in; (void)out_size; (void)ws_size;
  const float* rnn_x    = (const float*)d_in[0];
  const float* lstm_x   = (const float*)d_in[1];
  const float* rnn_Wih  = (const float*)d_in[2];
  const float* rnn_Whh  = (const float*)d_in[3];
  const float* rnn_bih  = (const float*)d_in[4];
  const float* rnn_bhh  = (const float*)d_in[5];
  const float* lstm_Wih = (const float*)d_in[6];
  const float* lstm_Whh = (const float*)d_in[7];
  const float* lstm_bih = (const float*)d_in[8];
  const float* lstm_bhh = (const float*)d_in[9];
  const float* fc_W     = (const float*)d_in[10];
  const float* fc_b     = (const float*)d_in[11];
  float* out = (float*)d_out;

  char* ws = (char*)d_ws; size_t off = 0;
  auto alloc = [&](size_t b)->char*{ char* p = ws + off; off += (b + 255) & ~(size_t)255; return p; };
  const size_t NE = (size_t)64*1024*256;
  u16*  wih_r = (u16*)alloc(2*256*256*2);
  u16*  wih_l = (u16*)alloc(2*1024*256*2);
  u16*  xr    = (u16*)alloc(NE*2);                 // rnn_x bf16 -> later y1R
  u16*  xl    = (u16*)alloc(NE*2);                 // lstm_x bf16 -> later y1L -> L2 yL dump
  u16*  projR = (u16*)alloc(NE*2);
  u16*  projL = (u16*)alloc(NE*4*2);
  unsigned* hbuf = (unsigned*)alloc(2*64*256*4);   // tagged h exchange
  float* feat = (float*)alloc(64*512*4);

  k_cvt<<<2048,256,0,stream>>>(rnn_x,  xr, (int)(NE/4));
  k_cvt<<<2048,256,0,stream>>>(lstm_x, xl, (int)(NE/4));
  k_cvt<<<64, 256,0,stream>>>(rnn_Wih,  wih_r, 2*256*256/4);
  k_cvt<<<256,256,0,stream>>>(lstm_Wih, wih_l, 2*1024*256/4);
  k_gemm<<<dim3(512,2),256,0,stream>>>(xr, wih_r, projR, 256);
  k_gemm<<<dim3(512,8),256,0,stream>>>(xl, wih_l, projL, 1024);
  k_rec<<<8,512,0,stream>>>(projR, rnn_Whh, rnn_bih, rnn_bhh, xr,
                            projL, lstm_Whh, lstm_bih, lstm_bhh, xl,
                            hbuf, nullptr, 0);
  k_gemm<<<dim3(512,2),256,0,stream>>>(xr, wih_r + 256*256,  projR, 256);
  k_gemm<<<dim3(512,8),256,0,stream>>>(xl, wih_l + 1024*256, projL, 1024);
  // layer-2: yL written into xl (dead) to keep vmcnt counts uniform
  k_rec<<<8,512,0,stream>>>(projR, rnn_Whh + 256*256, rnn_bih + 256, rnn_bhh + 256, nullptr,
                            projL, lstm_Whh + 1024*256, lstm_bih + 1024, lstm_bhh + 1024, xl,
                            hbuf, feat, 1);
  k_fc<<<32,256,0,stream>>>(feat, fc_W, fc_b, out);
}

// Round 4
// 14323.036 us; speedup vs baseline: 2.5502x; 1.5082x over previous
//
#include <hip/hip_runtime.h>
#include <stdint.h>

// ComplexModel: 2-layer RNN(tanh) + 2-layer LSTM + FC on MI355X (gfx950)
// B=64 T=1024 D=256 H=256 HL=256 L=2 C=128
#define T_ 1024

typedef short bf16x8 __attribute__((ext_vector_type(8)));
typedef float f32x4  __attribute__((ext_vector_type(4)));
typedef int   i32x4  __attribute__((ext_vector_type(4)));
typedef unsigned short u16;

#define MFMA(a,b,c) __builtin_amdgcn_mfma_f32_16x16x32_bf16((a),(b),(c),0,0,0)

__device__ __forceinline__ u16 f2bf(float f){
  unsigned u = __float_as_uint(f);
  return (u16)((u + 0x7FFFu + ((u>>16)&1u)) >> 16);   // RNE
}
__device__ __forceinline__ float bf2f(u16 s){ return __uint_as_float(((unsigned)s)<<16); }
__device__ __forceinline__ float sigm(float x){ return 1.f/(1.f+__expf(-x)); }
__device__ __forceinline__ float tanhq(float x){ return 2.f/(1.f+__expf(-2.f*x)) - 1.f; }

__device__ __forceinline__ void gload16(const void* g, void* l){
  __builtin_amdgcn_global_load_lds(
      (const __attribute__((address_space(1))) unsigned int*)g,
      (__attribute__((address_space(3)))       unsigned int*)l, 16, 0, 0);
}
__device__ __forceinline__ void lgkm0_barrier(){
  asm volatile("s_waitcnt lgkmcnt(0)" ::: "memory");
  __builtin_amdgcn_s_barrier();
  asm volatile("" ::: "memory");
}

#define VMCNT(n) do{ asm volatile("s_waitcnt vmcnt(" #n ")" ::: "memory"); \
                     __builtin_amdgcn_sched_barrier(0); }while(0)
// coherent (LLC-visible) ops
#define LD_X4(dst, p, OFF) asm volatile("global_load_dwordx4 %0, %1, off offset:" #OFF " sc0 sc1" : "=v"(dst) : "v"(p) : "memory")
#define ST_TAG(p, v, OFF)  asm volatile("global_store_dword %0, %1, off offset:" #OFF " sc0 sc1" :: "v"(p), "v"(v) : "memory")
// normal cached u16 load (proj is read-only, dispatch-boundary coherent)
#define LD_U16(dst, p, OFF) asm volatile("global_load_ushort %0, %1, off offset:" #OFF : "=v"(dst) : "v"(p) : "memory")

// ---------------- f32 -> bf16 conversion ----------------
__global__ void k_cvt(const float* __restrict__ s, u16* __restrict__ d, int n4){
  int i = blockIdx.x*blockDim.x + threadIdx.x;
  int stride = gridDim.x*blockDim.x;
  for (; i < n4; i += stride){
    float4 v = ((const float4*)s)[i];
    ushort4 o; o.x=f2bf(v.x); o.y=f2bf(v.y); o.z=f2bf(v.z); o.w=f2bf(v.w);
    ((ushort4*)d)[i] = o;
  }
}

// ---------------- bf16 GEMM: C[(t*64+b), N] = A[b*T+t][256] @ B[N,256]^T ----
__global__ __launch_bounds__(256,2) void k_gemm(
    const u16* __restrict__ A, const u16* __restrict__ Bm,
    u16* __restrict__ C, int N)
{
  __shared__ u16 As[128*64];
  __shared__ u16 Bs[128*64];
  const int tid = threadIdx.x;
  const int lane = tid & 63, w = tid >> 6;
  const int l15 = lane & 15, l4 = lane >> 4;
  const long m0 = (long)blockIdx.x * 128;
  const int  n0 = blockIdx.y * 128;
  const int  mo = (w>>1)*64, no = (w&1)*64;

  f32x4 acc[4][4];
  #pragma unroll
  for (int i=0;i<4;++i)
    #pragma unroll
    for (int j=0;j<4;++j) acc[i][j] = (f32x4){0.f,0.f,0.f,0.f};

  for (int kt=0; kt<4; ++kt){
    const int k0 = kt*64;
    #pragma unroll
    for (int i=0;i<4;++i){
      int fb = (i*256+tid)*16;
      int r  = fb>>7, cbyte = fb&127;
      gload16(A + (m0 + r)*256 + k0 + (cbyte>>1), (char*)As + fb);
      gload16(Bm + (long)(n0 + r)*256 + k0 + (cbyte>>1), (char*)Bs + fb);
    }
    __syncthreads();
    #pragma unroll
    for (int kb=0;kb<2;++kb){
      bf16x8 a[4], b[4];
      #pragma unroll
      for (int mb=0;mb<4;++mb)
        a[mb] = *(const bf16x8*)(As + (mo+mb*16+l15)*64 + kb*32 + l4*8);
      #pragma unroll
      for (int nb=0;nb<4;++nb)
        b[nb] = *(const bf16x8*)(Bs + (no+nb*16+l15)*64 + kb*32 + l4*8);
      #pragma unroll
      for (int mb=0;mb<4;++mb)
        #pragma unroll
        for (int nb=0;nb<4;++nb)
          acc[mb][nb] = MFMA(a[mb], b[nb], acc[mb][nb]);
    }
    __syncthreads();
  }
  #pragma unroll
  for (int mb=0;mb<4;++mb)
    #pragma unroll
    for (int nb=0;nb<4;++nb)
      #pragma unroll
      for (int j=0;j<4;++j){
        long m   = m0 + mo + mb*16 + l4*4 + j;       // m = b*1024 + t
        long crow= (long)(m & 1023)*64 + (m >> 10);  // -> t*64 + b
        int  col = n0 + no + nb*16 + l15;
        C[crow*N + col] = f2bf(acc[mb][nb][j]);
      }
}

// ---------------- fused recurrence kernel ----------------
// blocks 0..3 : RNN, batch-split (16 rows), Whh(hi/lo) in regs, h in LDS.
// blocks 4..11: LSTM, 8 slices x 32 units; 4 batch-chains pipelined per step;
//               tagged-dword h exchange (parity buf), 2-slot-ahead stage,
//               uniform 14 VMEM ops/slot -> provable counted vmcnt waits.
__global__ __launch_bounds__(512,2) void k_rec(
    const u16*  __restrict__ projR,  // [t*64+b][256] bf16
    const float* __restrict__ WhhR,
    const float* __restrict__ bihR, const float* __restrict__ bhhR,
    u16* __restrict__ yR,            // [b*T+t][256] bf16 or null
    const u16*  __restrict__ projL,  // [t*64+b][1024] bf16
    const float* __restrict__ WhhL,
    const float* __restrict__ bihL, const float* __restrict__ bhhL,
    u16* __restrict__ yL,            // [b*T+t][256] bf16 (L2: dead buf, keeps counts uniform)
    unsigned* __restrict__ hbuf,     // u32 [2][64][256]: (tag16<<16)|h_bf16
    float* __restrict__ feat,        // [64][512] f32 or null
    int lay)
{
  __shared__ u16 hlds[16*256];       // RNN h
  __shared__ u16 lsm[2*16*256];      // LSTM staged h (E/O x 8KB)
  const int tid = threadIdx.x;
  const int lane = tid & 63, w = tid >> 6;
  const int l15 = lane & 15, l4 = lane >> 4;
  const int bid = blockIdx.x;
  const unsigned tagbase = (unsigned)(lay << 12);

  if (bid < 4){
    // =============== RNN (proven; unchanged) ===============
    const int g = bid;
    const int cb = 32*w;
    bf16x8 bhi[2][8], blo[2][8];
    #pragma unroll
    for (int nb=0;nb<2;++nb){
      const int col = cb + nb*16 + l15;
      #pragma unroll
      for (int kb=0;kb<8;++kb){
        const float* wp = WhhR + (long)col*256 + kb*32 + l4*8;
        #pragma unroll
        for (int j=0;j<8;++j){
          float wv = wp[j];
          u16 hi = f2bf(wv);
          bhi[nb][kb][j] = (short)hi;
          blo[nb][kb][j] = (short)f2bf(wv - bf2f(hi));
        }
      }
    }
    float bias[2];
    #pragma unroll
    for (int nb=0;nb<2;++nb){ int col = cb+nb*16+l15; bias[nb]=bihR[col]+bhhR[col]; }

    u16 pfr[8];
    #pragma unroll
    for (int nb=0;nb<2;++nb)
      #pragma unroll
      for (int j=0;j<4;++j)
        pfr[nb*4+j] = projR[(long)(16*g + l4*4 + j)*256 + cb + nb*16 + l15];

    for (int t=0; t<T_; ++t){
      lgkm0_barrier();
      f32x4 acc0 = {0.f,0.f,0.f,0.f}, acc1 = acc0;
      if (t > 0){
        bf16x8 a[8];
        #pragma unroll
        for (int kb=0;kb<8;++kb){
          int bo = (l15*512 + kb*64 + l4*16) ^ ((l15&7)<<4);
          a[kb] = *(const bf16x8*)((const char*)hlds + bo);
        }
        #pragma unroll
        for (int kb=0;kb<8;++kb){
          acc0 = MFMA(a[kb], bhi[0][kb], acc0);
          acc0 = MFMA(a[kb], blo[0][kb], acc0);
          acc1 = MFMA(a[kb], bhi[1][kb], acc1);
          acc1 = MFMA(a[kb], blo[1][kb], acc1);
        }
      }
      float hv[2][4];
      #pragma unroll
      for (int nb=0;nb<2;++nb)
        #pragma unroll
        for (int j=0;j<4;++j){
          float pre = (nb ? acc1[j] : acc0[j]) + bf2f(pfr[nb*4+j]) + bias[nb];
          hv[nb][j] = tanhq(pre);
        }
      int tn = (t+1 < T_) ? t+1 : t;
      #pragma unroll
      for (int nb=0;nb<2;++nb)
        #pragma unroll
        for (int j=0;j<4;++j)
          pfr[nb*4+j] = projR[(long)(tn*64 + 16*g + l4*4 + j)*256 + cb + nb*16 + l15];
      lgkm0_barrier();
      #pragma unroll
      for (int nb=0;nb<2;++nb)
        #pragma unroll
        for (int j=0;j<4;++j){
          int m = l4*4 + j, u = cb + nb*16 + l15;
          u16 hb = f2bf(hv[nb][j]);
          int bo = (m*512 + u*2) ^ ((m&7)<<4);
          *(u16*)((char*)hlds + bo) = hb;
          if (yR) yR[((long)(16*g+m)*T_ + t)*256 + u] = hb;
          if (feat && t == T_-1) feat[(16*g+m)*512 + u] = hv[nb][j];
        }
    }
  } else {
    // =============== LSTM: 8 WGs x 32 units, 4 units/wave ===============
    const int hg = bid - 4;
    const int gl  = l15 >> 2;               // lane's gate (i,f,g,o = 0..3)
    const int ul  = 32*hg + 4*w + (l15&3);  // lane's unit
    const bool gl0 = (l15 < 4);
    const bool isG = (gl == 2);
    const bool wfeat = (feat != nullptr);
    const int srow  = tid >> 5;             // staged row this lane fills (0..15)
    const int scol8 = (tid & 31) * 8;       // dword col
    const int swro  = ((srow*512 + (tid&31)*16) ^ ((srow&7)<<4));
    char* lsmBE = (char*)lsm;
    char* lsmBO = (char*)lsm + 8192;

    bf16x8 bhi[8], blo[8];
    const long wr = (long)(gl*256 + ul);
    const float bias0 = bihL[wr] + bhhL[wr];
    #pragma unroll
    for (int kb=0;kb<8;++kb){
      const float* wp = WhhL + wr*256 + kb*32 + l4*8;
      #pragma unroll
      for (int j=0;j<8;++j){
        float wv = wp[j];
        u16 hi = f2bf(wv);
        bhi[kb][j] = (short)hi;
        blo[kb][j] = (short)f2bf(wv - bf2f(hi));
      }
    }
    float cst[4][4];
    #pragma unroll
    for (int b_=0;b_<4;++b_){ cst[b_][0]=0.f;cst[b_][1]=0.f;cst[b_][2]=0.f;cst[b_][3]=0.f; }
    i32x4 rE0, rE1, rO0, rO1;
    unsigned pfE[4], pfO[4];

    #define PFR4(PF, TT, BGC) do{                                                  \
      const u16* pb  = projL + ((size_t)(TT)*64 + 16*(BGC) + l4*4)*1024 + gl*256 + ul; \
      const u16* pb2 = pb + 2048;                                                  \
      LD_U16(PF[0], pb, 0);  LD_U16(PF[1], pb, 2048);                              \
      LD_U16(PF[2], pb2, 0); LD_U16(PF[3], pb2, 2048);                             \
    }while(0)

    // slot body: phase A (consume+pack), B (stage+2), barrier, D (mfma),
    // E (vmcnt), F (act + 4 ST_TAG + 4 yL), G (pfr+4)  => 14 VMEM ops/slot
    #define LSLOT(BG, RS, PF, LSB) do{                                             \
      if (t > 0){                                                                  \
        VMCNT(24);                                                                 \
        const unsigned tw = (tagbase | (unsigned)t) << 16;                         \
        for(;;){                                                                   \
          unsigned bad = (((unsigned)RS##0[0] ^ tw) | ((unsigned)RS##0[1] ^ tw)    \
                        | ((unsigned)RS##0[2] ^ tw) | ((unsigned)RS##0[3] ^ tw)    \
                        | ((unsigned)RS##1[0] ^ tw) | ((unsigned)RS##1[1] ^ tw)    \
                        | ((unsigned)RS##1[2] ^ tw) | ((unsigned)RS##1[3] ^ tw))   \
                        & 0xFFFF0000u;                                             \
          if (!__any(bad != 0u)) break;                                            \
          __builtin_amdgcn_s_sleep(8);                                             \
          const unsigned* sp = hbuf + (t&1)*16384 + (16*(BG) + srow)*256 + scol8;  \
          LD_X4(RS##0, sp, 0); LD_X4(RS##1, sp, 16);                               \
          VMCNT(0);                                                                \
        }                                                                          \
        i32x4 pk;                                                                  \
        pk[0]=(int)__builtin_amdgcn_perm((unsigned)RS##0[1],(unsigned)RS##0[0],0x05040100u); \
        pk[1]=(int)__builtin_amdgcn_perm((unsigned)RS##0[3],(unsigned)RS##0[2],0x05040100u); \
        pk[2]=(int)__builtin_amdgcn_perm((unsigned)RS##1[1],(unsigned)RS##1[0],0x05040100u); \
        pk[3]=(int)__builtin_amdgcn_perm((unsigned)RS##1[3],(unsigned)RS##1[2],0x05040100u); \
        *(i32x4*)(lsmB##LSB + swro) = pk;                                          \
      }                                                                            \
      { int tc = ((BG) >= 2) ? t+1 : t;  if (tc > T_-1) tc = T_-1;                 \
        const unsigned* sp = hbuf + (tc&1)*16384 + (16*(((BG)+2)&3) + srow)*256 + scol8; \
        LD_X4(RS##0, sp, 0); LD_X4(RS##1, sp, 16); }                               \
      asm volatile("s_waitcnt lgkmcnt(0)" ::: "memory");                           \
      __builtin_amdgcn_s_barrier();                                                \
      f32x4 acc = {0.f,0.f,0.f,0.f};                                               \
      if (t > 0){                                                                  \
        _Pragma("unroll")                                                          \
        for (int kb=0;kb<8;++kb){                                                  \
          bf16x8 a = *(const bf16x8*)(lsmB##LSB + ((l15*512 + kb*64 + l4*16) ^ ((l15&7)<<4))); \
          acc = MFMA(a, bhi[kb], acc);                                             \
          acc = MFMA(a, blo[kb], acc);                                             \
        }                                                                          \
      }                                                                            \
      VMCNT(14);                                                                   \
      { const unsigned tws = (tagbase | (unsigned)(t+1)) << 16;                    \
        unsigned* hb = hbuf + (((t+1)&1))*16384 + ((size_t)(16*(BG) + l4*4))*256 + ul; \
        _Pragma("unroll")                                                          \
        for (int j=0;j<4;++j){                                                     \
          float sv = acc[j] + bf2f((u16)PF[j]) + bias0;                            \
          float av = isG ? tanhq(sv) : sigm(sv);                                   \
          float fx = __shfl_xor(av, 4);                                            \
          float gx = __shfl_xor(av, 8);                                            \
          float ox = __shfl_xor(av, 12);                                           \
          float cv = fx * cst[BG][j] + av * gx;                                    \
          cst[BG][j] = cv;                                                         \
          float hval = ox * tanhq(cv);                                             \
          if (gl0){                                                                \
            u16 hb16 = f2bf(hval);                                                 \
            unsigned* ha = hb + j*256;                                             \
            ST_TAG(ha, tws | (unsigned)hb16, 0);                                   \
            yL[((long)(16*(BG) + l4*4 + j)*T_ + t)*256 + ul] = hb16;               \
            if (wfeat && t == T_-1) feat[(16*(BG)+l4*4+j)*512 + 256 + ul] = hval;  \
          }                                                                        \
        }                                                                          \
      }                                                                            \
      { int tp = ((BG) >= 2) ? t+1 : t;  if (tp > T_-1) tp = T_-1;                 \
        PFR4(PF, tp, ((BG)+2)&3); }                                                \
    }while(0)

    // prologue: preload pfr for slots (0,0),(0,1)
    PFR4(pfE, 0, 0);
    PFR4(pfO, 0, 1);
    VMCNT(0);

    for (int t=0; t<T_; ++t){
      LSLOT(0, rE, pfE, E);
      LSLOT(1, rO, pfO, O);
      LSLOT(2, rE, pfE, E);
      LSLOT(3, rO, pfO, O);
    }
    VMCNT(0);
  }
}

// ---------------- FC ----------------
__global__ void k_fc(const float* __restrict__ feat, const float* __restrict__ W,
                     const float* __restrict__ bias, float* __restrict__ out){
  int o = blockIdx.x*blockDim.x + threadIdx.x;
  if (o >= 64*128) return;
  int b = o >> 7, c = o & 127;
  float s = bias[c];
  const float* f  = feat + b*512;
  const float* wr = W + c*512;
  #pragma unroll 8
  for (int k=0;k<512;++k) s += f[k]*wr[k];
  out[o] = s;
}

extern "C" void kernel_launch(void* const* d_in, const int* in_sizes, int n_in,
                              void* d_out, int out_size, void* d_ws, size_t ws_size,
                              hipStream_t stream)
{
  (void)in_sizes; (void)n_in; (void)out_size; (void)ws_size;
  const float* rnn_x    = (const float*)d_in[0];
  const float* lstm_x   = (const float*)d_in[1];
  const float* rnn_Wih  = (const float*)d_in[2];
  const float* rnn_Whh  = (const float*)d_in[3];
  const float* rnn_bih  = (const float*)d_in[4];
  const float* rnn_bhh  = (const float*)d_in[5];
  const float* lstm_Wih = (const float*)d_in[6];
  const float* lstm_Whh = (const float*)d_in[7];
  const float* lstm_bih = (const float*)d_in[8];
  const float* lstm_bhh = (const float*)d_in[9];
  const float* fc_W     = (const float*)d_in[10];
  const float* fc_b     = (const float*)d_in[11];
  float* out = (float*)d_out;

  char* ws = (char*)d_ws; size_t off = 0;
  auto alloc = [&](size_t b)->char*{ char* p = ws + off; off += (b + 255) & ~(size_t)255; return p; };
  const size_t NE = (size_t)64*1024*256;
  u16*  wih_r = (u16*)alloc(2*256*256*2);
  u16*  wih_l = (u16*)alloc(2*1024*256*2);
  u16*  xr    = (u16*)alloc(NE*2);                 // rnn_x bf16 -> later y1R
  u16*  xl    = (u16*)alloc(NE*2);                 // lstm_x bf16 -> later y1L -> L2 dump
  u16*  projR = (u16*)alloc(NE*2);
  u16*  projL = (u16*)alloc(NE*4*2);
  unsigned* hbuf = (unsigned*)alloc(2*64*256*4);   // tagged h exchange
  float* feat = (float*)alloc(64*512*4);

  k_cvt<<<2048,256,0,stream>>>(rnn_x,  xr, (int)(NE/4));
  k_cvt<<<2048,256,0,stream>>>(lstm_x, xl, (int)(NE/4));
  k_cvt<<<64, 256,0,stream>>>(rnn_Wih,  wih_r, 2*256*256/4);
  k_cvt<<<256,256,0,stream>>>(lstm_Wih, wih_l, 2*1024*256/4);
  k_gemm<<<dim3(512,2),256,0,stream>>>(xr, wih_r, projR, 256);
  k_gemm<<<dim3(512,8),256,0,stream>>>(xl, wih_l, projL, 1024);
  k_rec<<<12,512,0,stream>>>(projR, rnn_Whh, rnn_bih, rnn_bhh, xr,
                             projL, lstm_Whh, lstm_bih, lstm_bhh, xl,
                             hbuf, nullptr, 0);
  k_gemm<<<dim3(512,2),256,0,stream>>>(xr, wih_r + 256*256,  projR, 256);
  k_gemm<<<dim3(512,8),256,0,stream>>>(xl, wih_l + 1024*256, projL, 1024);
  // layer-2: yL written into xl (dead after L2 GEMM) to keep VMEM counts uniform
  k_rec<<<12,512,0,stream>>>(projR, rnn_Whh + 256*256, rnn_bih + 256, rnn_bhh + 256, nullptr,
                             projL, lstm_Whh + 1024*256, lstm_bih + 1024, lstm_bhh + 1024, xl,
                             hbuf, feat, 1);
  k_fc<<<32,256,0,stream>>>(feat, fc_W, fc_b, out);
}